// Round 6
// baseline (109.607 us; speedup 1.0000x reference)
//
#include <hip/hip_runtime.h>
#include <hip/hip_bf16.h>

typedef unsigned short u16;
typedef unsigned int u32;
typedef unsigned long long u64;
typedef __attribute__((ext_vector_type(8))) short short8;
typedef __attribute__((ext_vector_type(4))) float floatx4;

#define NB 32
#define NCI 256
#define NCO 256
#define NW 4096
#define NK 5

#define W3ROWB 80                      // 32 bf16 (64B) + 16B pad per co-row
#define W3TILE (256 * W3ROWB)          // 20480 B per (cb,tap) tile
#define W3_BYTES (40 * W3TILE)         // 819200

#define XROWB 64                       // LDS X row: 32 ci' bf16, XOR-swizzled slots
#define XROWS 264                      // w0-4 .. w0+259 (halo baked in)
#define XBUF (XROWS * XROWB)           // 16896 B

// swizzle: 16-B slot XOR within 64-B row; spreads any 8 consecutive rows
// across all 8 bank-slot classes (conflict-free b128 read AND write)
#define XSWZ(row) ((((row) >> 1) & 3) << 4)

// ---------------- pre-kernel: W fp32 -> bf16, [cb,t][co][ci'] 80B rows ----------------

__global__ void wprep(const float* __restrict__ wgt, u16* __restrict__ W3) {
    int i = blockIdx.x * 256 + threadIdx.x;       // co*1280 + ci*5 + k
    if (i >= NCO * NCI * NK) return;
    int k  = i % NK;
    int ci = (i / NK) % NCI;
    int co = i / (NCI * NK);
    int cb = ci >> 5, cr = ci & 31;
    __hip_bfloat16 h = __float2bfloat16(wgt[i]);
    W3[((size_t)(cb * NK + k) * 256 + co) * 40 + cr] = *reinterpret_cast<u16*>(&h);
}

__device__ __forceinline__ u16 bf16bits(float f) {
    __hip_bfloat16 h = __float2bfloat16(f);
    return *reinterpret_cast<u16*>(&h);
}

// ---------------- fused conv ----------------
// grid 512 = 16 w-tiles x 32 batch; block 512 thr = 8 waves.
// block tile 256co x 256w; wave tile 128co x 64w (wm=wave>>2, wn=wave&3);
// mfma_f32_16x16x32_bf16, acc[8][4] floatx4.
// af from global W3 (L1/L2-hot); bf from LDS X (swizzled, dbuf, T14, 1 barrier/cb).

__global__ __launch_bounds__(512, 2)
void conv_mfma(const float* __restrict__ x, const u16* __restrict__ W3,
               const float* __restrict__ bias, float* __restrict__ out) {
    __shared__ __align__(16) char xlds[2 * XBUF];   // 33792 B

    const int bid  = blockIdx.x;
    const int wt   = bid & 15;
    const int b    = bid >> 4;
    const int tid  = threadIdx.x;
    const int lane = tid & 63;
    const int wave = tid >> 6;
    const int wm   = wave >> 2;        // co strip: wm*128
    const int wn   = wave & 3;         // w strip:  wn*64
    const int mrow = lane & 15;
    const int g    = lane >> 4;        // 0..3
    const int w0   = wt * 256;

    floatx4 acc[8][4];
#pragma unroll
    for (int mi = 0; mi < 8; ++mi)
#pragma unroll
        for (int ni = 0; ni < 4; ++ni)
            acc[mi][ni] = (floatx4){0.f, 0.f, 0.f, 0.f};

    const float* xb = x + (size_t)b * NCI * NW;

    // main-stage mapping: 2 threads per X row; each covers 16 contiguous ci
    const int srow = tid & 255;        // local w index 0..255 -> LDS row srow+4
    const int h    = tid >> 8;         // ci half: h*16 .. h*16+15
    // precomputed physical int4 slots for this thread's row
    char* const sdst0_base = xlds + (srow + 4) * XROWB + ((h * 32) ^ XSWZ(srow + 4));
    char* const sdst1_base = xlds + (srow + 4) * XROWB + ((h * 32 + 16) ^ XSWZ(srow + 4));

    // halo task (threads 0..63): side 0 -> rows 0..3 (w0-4..w0-1), side 1 -> rows 260..263
    const int hside = tid >> 5;
    const int hr    = (tid >> 3) & 3;
    const int hcq   = tid & 7;         // 4 ci each (u64)
    const int hrow  = hside ? (260 + hr) : hr;
    const int hwg   = hside ? (w0 + 256 + hr) : (w0 - 4 + hr);
    const bool hvalid = (hwg >= 0) && (hwg < NW);
    const int hoff  = hrow * XROWB + ((hcq * 8) ^ XSWZ(hrow));

    // ---------- prologue: stage cb = 0 into buf 0 ----------
    {
        float v[16];
        float hv[4] = {0.f, 0.f, 0.f, 0.f};
#pragma unroll
        for (int j = 0; j < 16; ++j)
            v[j] = xb[(size_t)(h * 16 + j) * NW + w0 + srow];
        if (tid < 64 && hvalid)
#pragma unroll
            for (int q = 0; q < 4; ++q)
                hv[q] = xb[(size_t)(hcq * 4 + q) * NW + hwg];

        u32 p[8];
#pragma unroll
        for (int j = 0; j < 8; ++j)
            p[j] = (u32)bf16bits(v[2 * j]) | ((u32)bf16bits(v[2 * j + 1]) << 16);
        *(int4*)sdst0_base = *(int4*)&p[0];
        *(int4*)sdst1_base = *(int4*)&p[4];
        if (tid < 64) {
            u64 hp = (u64)bf16bits(hv[0]) | ((u64)bf16bits(hv[1]) << 16) |
                     ((u64)bf16bits(hv[2]) << 32) | ((u64)bf16bits(hv[3]) << 48);
            *(u64*)(xlds + hoff) = hp;
        }
    }
    __syncthreads();

    // ---------- main loop over 8 ci-blocks ----------
    for (int cb = 0; cb < 8; ++cb) {
        const char* cur = xlds + (cb & 1) * XBUF;
        char* nxt       = xlds + ((cb + 1) & 1) * XBUF;
        const bool more = (cb < 7);

        // T14 issue-early: global loads for cb+1
        float v[16];
        float hv[4] = {0.f, 0.f, 0.f, 0.f};
        if (more) {
            const float* xcb = xb + (size_t)((cb + 1) * 32) * NW;
#pragma unroll
            for (int j = 0; j < 16; ++j)
                v[j] = xcb[(size_t)(h * 16 + j) * NW + w0 + srow];
            if (tid < 64 && hvalid)
#pragma unroll
                for (int q = 0; q < 4; ++q)
                    hv[q] = xcb[(size_t)(hcq * 4 + q) * NW + hwg];
        }

        // compute cb: 5 taps x (8 af-global + 4 bf-LDS + 32 MFMA)
#pragma unroll
        for (int t = 0; t < NK; ++t) {
            const char* wtile = (const char*)W3 + (size_t)(cb * NK + t) * W3TILE;
            short8 af[8], bf[4];
#pragma unroll
            for (int mi = 0; mi < 8; ++mi)
                af[mi] = *(const short8*)(wtile +
                         (wm * 128 + mi * 16 + mrow) * W3ROWB + g * 16);
#pragma unroll
            for (int ni = 0; ni < 4; ++ni) {
                int rowx = wn * 64 + ni * 16 + mrow + t + 2;
                bf[ni] = *(const short8*)(cur + rowx * XROWB + ((g * 16) ^ XSWZ(rowx)));
            }

            __builtin_amdgcn_s_setprio(1);
#pragma unroll
            for (int mi = 0; mi < 8; ++mi)
#pragma unroll
                for (int ni = 0; ni < 4; ++ni)
                    acc[mi][ni] = __builtin_amdgcn_mfma_f32_16x16x32_bf16(
                        af[mi], bf[ni], acc[mi][ni], 0, 0, 0);
            __builtin_amdgcn_s_setprio(0);
        }

        // T14 write-late: pack + ds_write into the other buffer, then barrier
        if (more) {
            u32 p[8];
#pragma unroll
            for (int j = 0; j < 8; ++j)
                p[j] = (u32)bf16bits(v[2 * j]) | ((u32)bf16bits(v[2 * j + 1]) << 16);
            *(int4*)(nxt + (sdst0_base - xlds)) = *(int4*)&p[0];
            *(int4*)(nxt + (sdst1_base - xlds)) = *(int4*)&p[4];
            if (tid < 64) {
                u64 hp = (u64)bf16bits(hv[0]) | ((u64)bf16bits(hv[1]) << 16) |
                         ((u64)bf16bits(hv[2]) << 32) | ((u64)bf16bits(hv[3]) << 48);
                *(u64*)(nxt + hoff) = hp;
            }
            __syncthreads();
        }
    }

    // ---------- epilogue: C/D col=lane&15 (w), row=g*4+r (co) ----------
#pragma unroll
    for (int mi = 0; mi < 8; ++mi) {
        int cobase = wm * 128 + mi * 16 + g * 4;
        float bv[4];
#pragma unroll
        for (int r = 0; r < 4; ++r) bv[r] = bias[cobase + r];
#pragma unroll
        for (int ni = 0; ni < 4; ++ni) {
            int col = w0 + wn * 64 + ni * 16 + mrow;
#pragma unroll
            for (int r = 0; r < 4; ++r)
                out[((size_t)b * NCO + cobase + r) * NW + col] =
                    acc[mi][ni][r] + bv[r];
        }
    }
}

// ---------------- fallback (ws too small): naive fp32 ----------------

__global__ void conv_naive(const float* __restrict__ x, const float* __restrict__ wgt,
                           const float* __restrict__ bias, float* __restrict__ out) {
    int w  = blockIdx.x * 256 + threadIdx.x;
    int co = blockIdx.y;
    int b  = blockIdx.z;
    float acc = bias[co];
    for (int ci = 0; ci < NCI; ci++) {
        const float* xr = x + ((size_t)b * NCI + ci) * NW;
        const float* wr = wgt + ((size_t)co * NCI + ci) * NK;
#pragma unroll
        for (int k = 0; k < NK; k++) {
            int wi = w + k - 2;
            if (wi >= 0 && wi < NW) acc += xr[wi] * wr[k];
        }
    }
    out[((size_t)b * NCO + co) * NW + w] = acc;
}

// ---------------- launch ----------------

extern "C" void kernel_launch(void* const* d_in, const int* in_sizes, int n_in,
                              void* d_out, int out_size, void* d_ws, size_t ws_size,
                              hipStream_t stream) {
    const float* x    = (const float*)d_in[0];
    const float* wgt  = (const float*)d_in[1];
    const float* bias = (const float*)d_in[2];
    float* out        = (float*)d_out;

    if (ws_size < (size_t)W3_BYTES) {
        conv_naive<<<dim3(NW / 256, NCO, NB), 256, 0, stream>>>(x, wgt, bias, out);
        return;
    }

    u16* W3 = (u16*)d_ws;
    wprep<<<(NCO * NCI * NK + 255) / 256, 256, 0, stream>>>(wgt, W3);
    conv_mfma<<<512, 512, 0, stream>>>(x, W3, bias, out);
}

// Round 7
// 106.819 us; speedup vs baseline: 1.0261x; 1.0261x over previous
//
#include <hip/hip_runtime.h>
#include <hip/hip_bf16.h>

typedef unsigned short u16;
typedef unsigned int u32;
typedef unsigned long long u64;
typedef __attribute__((ext_vector_type(8))) short short8;
typedef __attribute__((ext_vector_type(4))) float floatx4;

#define NB 32
#define NCI 256
#define NCO 256
#define NW 4096
#define NK 5

#define W4TILE 81920                   // per-cb tile: 5 taps x 256 co x 64 B (pre-swizzled)
#define W4_BYTES (8 * W4TILE)          // 655360
#define WLDS W4TILE                    // single-buffered in LDS

#define XROWB 64                       // LDS X row: 32 ci' bf16, XOR-swizzled slots
#define XROWS 264                      // w0-4 .. w0+259 (halo baked in)
#define XBUF (XROWS * XROWB)           // 16896 B

// 16-B slot XOR within 64-B row; any 8 consecutive rows hit all 8 bank-slot
// classes exactly once -> conflict-free b128 read AND write
#define XSWZ(row) ((((row) >> 1) & 3) << 4)

// ---------------- pre-kernel: W fp32 -> bf16, pre-swizzled DMA image ----------------
// image: per cb, row = k*256 + co (64 B), 16-B slot stored at (slot ^ XSWZ(row))
// so a LINEAR global_load_lds lands data at the swizzled LDS position (T21).

__global__ void wprep(const float* __restrict__ wgt, u16* __restrict__ W4) {
    int i = blockIdx.x * 256 + threadIdx.x;       // co*1280 + ci*5 + k
    if (i >= NCO * NCI * NK) return;
    int k  = i % NK;
    int ci = (i / NK) % NCI;
    int co = i / (NCI * NK);
    int cb = ci >> 5, cr = ci & 31;
    int row  = k * 256 + co;
    int slot = (cr >> 3) ^ (((row >> 1) & 3));    // phys 16-B slot
    __hip_bfloat16 h = __float2bfloat16(wgt[i]);
    W4[(size_t)cb * (W4TILE / 2) + row * 32 + slot * 8 + (cr & 7)] =
        *reinterpret_cast<u16*>(&h);
}

__device__ __forceinline__ u16 bf16bits(float f) {
    __hip_bfloat16 h = __float2bfloat16(f);
    return *reinterpret_cast<u16*>(&h);
}

__device__ __forceinline__ void gload_lds16(const void* gsrc, void* ldst) {
    __builtin_amdgcn_global_load_lds(
        (const __attribute__((address_space(1))) unsigned int*)gsrc,
        (__attribute__((address_space(3))) unsigned int*)ldst, 16, 0, 0);
}

// ---------------- fused conv ----------------
// grid 512 = 16 w-tiles x 32 batch; block 512 thr = 8 waves.
// block tile 256co x 256w; wave tile 128co x 64w; mfma_f32_16x16x32_bf16.
// Compute phase reads ONLY LDS (af from wlds, bf from xlds) -> no vmcnt wait
// in the MFMA path. x T14 loads are the only vmem in flight during compute.
// W staged whole-cb (80 KB) via global_load_lds DMA between two barriers.

__global__ __launch_bounds__(512, 2)
void conv_mfma(const float* __restrict__ x, const u16* __restrict__ W4,
               const float* __restrict__ bias, float* __restrict__ out) {
    __shared__ __align__(16) char smem[WLDS + 2 * XBUF];   // 115712 B
    char* const wlds = smem;
    char* const xlds = smem + WLDS;

    const int bid  = blockIdx.x;
    const int wt   = bid & 15;
    const int b    = bid >> 4;
    const int tid  = threadIdx.x;
    const int lane = tid & 63;
    const int wave = tid >> 6;
    const int wm   = wave >> 2;        // co strip: wm*128
    const int wn   = wave & 3;         // w strip:  wn*64
    const int mrow = lane & 15;
    const int g    = lane >> 4;        // 0..3
    const int w0   = wt * 256;

    floatx4 acc[8][4];
#pragma unroll
    for (int mi = 0; mi < 8; ++mi)
#pragma unroll
        for (int ni = 0; ni < 4; ++ni)
            acc[mi][ni] = (floatx4){0.f, 0.f, 0.f, 0.f};

    const float* xb = x + (size_t)b * NCI * NW;
    const char*  wimg = (const char*)W4;

    // x staging: 2 threads per row; each covers 16 contiguous ci
    const int srow = tid & 255;        // local w -> LDS row srow+4
    const int h    = tid >> 8;         // ci half
    const int soff0 = (srow + 4) * XROWB + ((h * 32) ^ XSWZ(srow + 4));
    const int soff1 = (srow + 4) * XROWB + ((h * 32 + 16) ^ XSWZ(srow + 4));

    // halo task (threads 0..63)
    const int hside = tid >> 5;
    const int hr    = (tid >> 3) & 3;
    const int hcq   = tid & 7;
    const int hrow  = hside ? (260 + hr) : hr;
    const int hwg   = hside ? (w0 + 256 + hr) : (w0 - 4 + hr);
    const bool hvalid = (hwg >= 0) && (hwg < NW);
    const int hoff  = hrow * XROWB + ((hcq * 8) ^ XSWZ(hrow));

    // ---------- prologue: DMA W(0), reg-stage x(0) ----------
    {
#pragma unroll
        for (int k = 0; k < 10; ++k) {
            int c = wave + 8 * k;      // 80 chunks of 1 KB
            gload_lds16(wimg + c * 1024 + lane * 16, wlds + c * 1024);
        }
        float v[16];
        float hv[4] = {0.f, 0.f, 0.f, 0.f};
#pragma unroll
        for (int j = 0; j < 16; ++j)
            v[j] = xb[(size_t)(h * 16 + j) * NW + w0 + srow];
        if (tid < 64 && hvalid)
#pragma unroll
            for (int q = 0; q < 4; ++q)
                hv[q] = xb[(size_t)(hcq * 4 + q) * NW + hwg];

        u32 p[8];
#pragma unroll
        for (int j = 0; j < 8; ++j)
            p[j] = (u32)bf16bits(v[2 * j]) | ((u32)bf16bits(v[2 * j + 1]) << 16);
        *(int4*)(xlds + soff0) = *(int4*)&p[0];
        *(int4*)(xlds + soff1) = *(int4*)&p[4];
        if (tid < 64) {
            u64 hp = (u64)bf16bits(hv[0]) | ((u64)bf16bits(hv[1]) << 16) |
                     ((u64)bf16bits(hv[2]) << 32) | ((u64)bf16bits(hv[3]) << 48);
            *(u64*)(xlds + hoff) = hp;
        }
    }
    __syncthreads();   // drains DMA (vmcnt) + ds_writes (lgkmcnt)

    // ---------- main loop over 8 ci-blocks ----------
    for (int cb = 0; cb < 8; ++cb) {
        const char* cur = xlds + (cb & 1) * XBUF;
        char* nxt       = xlds + ((cb + 1) & 1) * XBUF;
        const bool more = (cb < 7);

        // T14 issue-early: x global loads for cb+1 (only vmem in flight)
        float v[16];
        float hv[4] = {0.f, 0.f, 0.f, 0.f};
        if (more) {
            const float* xcb = xb + (size_t)((cb + 1) * 32) * NW;
#pragma unroll
            for (int j = 0; j < 16; ++j)
                v[j] = xcb[(size_t)(h * 16 + j) * NW + w0 + srow];
            if (tid < 64 && hvalid)
#pragma unroll
                for (int q = 0; q < 4; ++q)
                    hv[q] = xcb[(size_t)(hcq * 4 + q) * NW + hwg];
        }

        // compute: 5 taps, af + bf both from LDS (lgkmcnt only)
#pragma unroll
        for (int t = 0; t < NK; ++t) {
            short8 af[8], bf[4];
#pragma unroll
            for (int mi = 0; mi < 8; ++mi) {
                int roww = t * 256 + wm * 128 + mi * 16 + mrow;
                af[mi] = *(const short8*)(wlds + roww * 64 + ((g * 16) ^ XSWZ(roww)));
            }
#pragma unroll
            for (int ni = 0; ni < 4; ++ni) {
                int rowx = wn * 64 + ni * 16 + mrow + t + 2;
                bf[ni] = *(const short8*)(cur + rowx * XROWB + ((g * 16) ^ XSWZ(rowx)));
            }

            __builtin_amdgcn_s_setprio(1);
#pragma unroll
            for (int mi = 0; mi < 8; ++mi)
#pragma unroll
                for (int ni = 0; ni < 4; ++ni)
                    acc[mi][ni] = __builtin_amdgcn_mfma_f32_16x16x32_bf16(
                        af[mi], bf[ni], acc[mi][ni], 0, 0, 0);
            __builtin_amdgcn_s_setprio(0);
        }

        if (more) {
            __syncthreads();   // all reads of wlds/cur done (drains x loads too — 5 taps old)

            // DMA W(cb+1) into wlds (regless; drained at next barrier)
#pragma unroll
            for (int k = 0; k < 10; ++k) {
                int c = wave + 8 * k;
                gload_lds16(wimg + (size_t)(cb + 1) * W4TILE + c * 1024 + lane * 16,
                            wlds + c * 1024);
            }

            // pack + ds_write x(cb+1)
            u32 p[8];
#pragma unroll
            for (int j = 0; j < 8; ++j)
                p[j] = (u32)bf16bits(v[2 * j]) | ((u32)bf16bits(v[2 * j + 1]) << 16);
            *(int4*)(nxt + soff0) = *(int4*)&p[0];
            *(int4*)(nxt + soff1) = *(int4*)&p[4];
            if (tid < 64) {
                u64 hp = (u64)bf16bits(hv[0]) | ((u64)bf16bits(hv[1]) << 16) |
                         ((u64)bf16bits(hv[2]) << 32) | ((u64)bf16bits(hv[3]) << 48);
                *(u64*)(nxt + hoff) = hp;
            }
            __syncthreads();   // W DMA + x writes visible
        }
    }

    // ---------- epilogue: C/D col=lane&15 (w), row=g*4+r (co) ----------
#pragma unroll
    for (int mi = 0; mi < 8; ++mi) {
        int cobase = wm * 128 + mi * 16 + g * 4;
        float bv[4];
#pragma unroll
        for (int r = 0; r < 4; ++r) bv[r] = bias[cobase + r];
#pragma unroll
        for (int ni = 0; ni < 4; ++ni) {
            int col = w0 + wn * 64 + ni * 16 + mrow;
#pragma unroll
            for (int r = 0; r < 4; ++r)
                out[((size_t)b * NCO + cobase + r) * NW + col] =
                    acc[mi][ni][r] + bv[r];
        }
    }
}

// ---------------- fallback (ws too small): naive fp32 ----------------

__global__ void conv_naive(const float* __restrict__ x, const float* __restrict__ wgt,
                           const float* __restrict__ bias, float* __restrict__ out) {
    int w  = blockIdx.x * 256 + threadIdx.x;
    int co = blockIdx.y;
    int b  = blockIdx.z;
    float acc = bias[co];
    for (int ci = 0; ci < NCI; ci++) {
        const float* xr = x + ((size_t)b * NCI + ci) * NW;
        const float* wr = wgt + ((size_t)co * NCI + ci) * NK;
#pragma unroll
        for (int k = 0; k < NK; k++) {
            int wi = w + k - 2;
            if (wi >= 0 && wi < NW) acc += xr[wi] * wr[k];
        }
    }
    out[((size_t)b * NCO + co) * NW + w] = acc;
}

// ---------------- launch ----------------

extern "C" void kernel_launch(void* const* d_in, const int* in_sizes, int n_in,
                              void* d_out, int out_size, void* d_ws, size_t ws_size,
                              hipStream_t stream) {
    const float* x    = (const float*)d_in[0];
    const float* wgt  = (const float*)d_in[1];
    const float* bias = (const float*)d_in[2];
    float* out        = (float*)d_out;

    if (ws_size < (size_t)W4_BYTES) {
        conv_naive<<<dim3(NW / 256, NCO, NB), 256, 0, stream>>>(x, wgt, bias, out);
        return;
    }

    u16* W4 = (u16*)d_ws;
    wprep<<<(NCO * NCI * NK + 255) / 256, 256, 0, stream>>>(wgt, W4);
    conv_mfma<<<512, 512, 0, stream>>>(x, W4, bias, out);
}